// Round 1
// baseline (187.107 us; speedup 1.0000x reference)
//
#include <hip/hip_runtime.h>

#define BB 128
#define DD 8732
#define OO 16
#define CC 21
#define THREADS 256

struct Accum { float loc_sl1; float conf_pos; float conf_neg; int n_pos; };

__device__ __forceinline__ float smoothl1(float d) {
    float ad = fabsf(d);
    return (ad < 1.0f) ? 0.5f * d * d : ad - 0.5f;
}

// One block per image: IoU matching, encode, SmoothL1 partials, n_pos.
__global__ __launch_bounds__(THREADS) void match_kernel(
    const float4* __restrict__ loc_pred,   // [B*D] xyzw = 4 coords
    const float4* __restrict__ gt_boxes,   // [B*O] xyxy
    const int*    __restrict__ gt_labels,  // [B*O]
    const float4* __restrict__ db,         // [D] cxcywh
    unsigned char* __restrict__ conf_t,    // [B*D] matched labels 0..20
    int*          __restrict__ n_positive, // [B]
    Accum*        __restrict__ acc)
{
    const int b = blockIdx.x;
    const int tid = threadIdx.x;

    __shared__ float s_ax1[OO], s_ay1[OO], s_ax2[OO], s_ay2[OO], s_area[OO];
    __shared__ int s_lab[OO];
    __shared__ int s_bdi[OO];
    __shared__ float s_ovl[DD];            // best truth overlap per prior
    __shared__ unsigned char s_idx[DD];    // best truth idx per prior
    __shared__ float r_val[THREADS];
    __shared__ int   r_idx[THREADS];

    if (tid < OO) {
        float4 g = gt_boxes[b * OO + tid];
        s_ax1[tid] = g.x; s_ay1[tid] = g.y; s_ax2[tid] = g.z; s_ay2[tid] = g.w;
        s_area[tid] = (g.z - g.x) * (g.w - g.y);
        s_lab[tid] = gt_labels[b * OO + tid];
    }
    __syncthreads();

    // per-o running argmax over d (this thread's strided d's, ascending)
    float bm_val[OO];
    int   bm_idx[OO];
    #pragma unroll
    for (int o = 0; o < OO; ++o) { bm_val[o] = -1.0f; bm_idx[o] = 0; }

    for (int d = tid; d < DD; d += THREADS) {
        float4 p = db[d];
        float px1 = p.x - p.z * 0.5f;
        float py1 = p.y - p.w * 0.5f;
        float px2 = p.x + p.z * 0.5f;
        float py2 = p.y + p.w * 0.5f;
        float area_b = (px2 - px1) * (py2 - py1);
        float best = -1.0f; int bi = 0;
        #pragma unroll
        for (int o = 0; o < OO; ++o) {
            float ltx = fmaxf(s_ax1[o], px1);
            float lty = fmaxf(s_ay1[o], py1);
            float rbx = fminf(s_ax2[o], px2);
            float rby = fminf(s_ay2[o], py2);
            float w = fmaxf(rbx - ltx, 0.0f);
            float h = fmaxf(rby - lty, 0.0f);
            float inter = w * h;
            float iou = inter / (s_area[o] + area_b - inter);
            if (iou > best) { best = iou; bi = o; }          // first-occurrence over o
            if (iou > bm_val[o]) { bm_val[o] = iou; bm_idx[o] = d; }  // first over d (ascending)
        }
        s_ovl[d] = best;
        s_idx[d] = (unsigned char)bi;
    }
    __syncthreads();

    // best_default_idx[o] = argmax_d iou (first occurrence -> smaller idx on tie)
    for (int o = 0; o < OO; ++o) {
        r_val[tid] = bm_val[o]; r_idx[tid] = bm_idx[o];
        __syncthreads();
        for (int s = THREADS / 2; s > 0; s >>= 1) {
            if (tid < s) {
                float v2 = r_val[tid + s]; int i2 = r_idx[tid + s];
                if (v2 > r_val[tid] || (v2 == r_val[tid] && i2 < r_idx[tid])) {
                    r_val[tid] = v2; r_idx[tid] = i2;
                }
            }
            __syncthreads();
        }
        if (tid == 0) s_bdi[o] = r_idx[0];
        __syncthreads();
    }

    // sequential scatter: ascending o, last write wins (XLA scatter behavior)
    if (tid == 0) {
        for (int o = 0; o < OO; ++o) {
            int ds = s_bdi[o];
            s_idx[ds] = (unsigned char)o;
            s_ovl[ds] = 1.0f;
        }
    }
    __syncthreads();

    int npos = 0;
    float sl1 = 0.0f;
    for (int d = tid; d < DD; d += THREADS) {
        int idx = s_idx[d];
        float ovl = s_ovl[d];
        int lab = (ovl < 0.5f) ? 0 : s_lab[idx];
        conf_t[(size_t)b * DD + d] = (unsigned char)lab;
        if (lab > 0) {
            ++npos;
            float ax1 = s_ax1[idx], ay1 = s_ay1[idx], ax2 = s_ax2[idx], ay2 = s_ay2[idx];
            float cx = (ax1 + ax2) * 0.5f;
            float cy = (ay1 + ay2) * 0.5f;
            float w  = ax2 - ax1, h = ay2 - ay1;
            float4 p = db[d];
            float gx = (cx - p.x) / (p.z / 10.0f);
            float gy = (cy - p.y) / (p.w / 10.0f);
            float gw = logf(w / p.z) * 5.0f;
            float gh = logf(h / p.w) * 5.0f;
            float4 lp = loc_pred[(size_t)b * DD + d];
            sl1 += smoothl1(lp.x - gx) + smoothl1(lp.y - gy)
                 + smoothl1(lp.z - gw) + smoothl1(lp.w - gh);
        }
    }
    r_val[tid] = sl1; r_idx[tid] = npos;
    __syncthreads();
    for (int s = THREADS / 2; s > 0; s >>= 1) {
        if (tid < s) { r_val[tid] += r_val[tid + s]; r_idx[tid] += r_idx[tid + s]; }
        __syncthreads();
    }
    if (tid == 0) {
        n_positive[b] = r_idx[0];
        atomicAdd(&acc->n_pos, r_idx[0]);
        atomicAdd(&acc->loc_sl1, r_val[0]);
    }
}

// one thread per (b,d): log-softmax CE over C=21 classes
__global__ __launch_bounds__(THREADS) void ce_kernel(
    const float* __restrict__ cls,
    const unsigned char* __restrict__ conf_t,
    float* __restrict__ ce_neg,
    Accum* __restrict__ acc)
{
    const size_t i = (size_t)blockIdx.x * THREADS + threadIdx.x;
    float cepos = 0.0f;
    if (i < (size_t)BB * DD) {
        const float* x = cls + i * CC;
        float v[CC];
        #pragma unroll
        for (int c = 0; c < CC; ++c) v[c] = x[c];
        float m = v[0];
        #pragma unroll
        for (int c = 1; c < CC; ++c) m = fmaxf(m, v[c]);
        float s = 0.0f;
        #pragma unroll
        for (int c = 0; c < CC; ++c) s += expf(v[c] - m);
        float lse = m + logf(s);
        int lab = (int)conf_t[i];
        float xl = x[lab];               // re-load (L1 hit) -> keeps v[] statically indexed
        float ce = lse - xl;
        if (lab > 0) { cepos = ce; ce_neg[i] = 0.0f; }
        else         { ce_neg[i] = ce; }
    }
    __shared__ float r[THREADS];
    r[threadIdx.x] = cepos;
    __syncthreads();
    for (int s = THREADS / 2; s > 0; s >>= 1) {
        if (threadIdx.x < s) r[threadIdx.x] += r[threadIdx.x + s];
        __syncthreads();
    }
    if (threadIdx.x == 0) atomicAdd(&acc->conf_pos, r[0]);
}

// one block per image: sum of top (3*n_pos) values of ce_neg row.
// Binary search the k-th largest value over non-negative float bit patterns.
__global__ __launch_bounds__(THREADS) void topk_kernel(
    const float* __restrict__ ce_neg,
    const int* __restrict__ n_positive,
    Accum* __restrict__ acc)
{
    const int b = blockIdx.x;
    const int tid = threadIdx.x;
    __shared__ float s[DD];
    __shared__ float r_f[THREADS];
    __shared__ int   r_i[THREADS];
    __shared__ int   s_bcast;

    for (int d = tid; d < DD; d += THREADS) s[d] = ce_neg[(size_t)b * DD + d];

    int k = 3 * n_positive[b];
    if (k <= 0) return;                 // uniform across block
    if (k > DD) k = DD;
    __syncthreads();

    // invariant: cnt(v >= f(lo)) >= k, cnt(v >= f(hi)) < k
    unsigned lo = 0u, hi = 0x7f800000u;
    while (hi - lo > 1u) {
        unsigned mid = lo + ((hi - lo) >> 1);
        float t = __uint_as_float(mid);
        int c = 0;
        for (int d = tid; d < DD; d += THREADS) c += (s[d] >= t) ? 1 : 0;
        r_i[tid] = c;
        __syncthreads();
        for (int st = THREADS / 2; st > 0; st >>= 1) {
            if (tid < st) r_i[tid] += r_i[tid + st];
            __syncthreads();
        }
        if (tid == 0) s_bcast = r_i[0];
        __syncthreads();
        int cnt = s_bcast;
        __syncthreads();
        if (cnt >= k) lo = mid; else hi = mid;
    }
    float vk = __uint_as_float(lo);     // k-th largest value

    float ssum = 0.0f; int cgt = 0;
    for (int d = tid; d < DD; d += THREADS) {
        float v = s[d];
        if (v > vk) { ssum += v; ++cgt; }
    }
    r_f[tid] = ssum; r_i[tid] = cgt;
    __syncthreads();
    for (int st = THREADS / 2; st > 0; st >>= 1) {
        if (tid < st) { r_f[tid] += r_f[tid + st]; r_i[tid] += r_i[tid + st]; }
        __syncthreads();
    }
    if (tid == 0) {
        float row = r_f[0] + (float)(k - r_i[0]) * vk;  // exact tie handling at v_k
        atomicAdd(&acc->conf_neg, row);
    }
}

__global__ void finalize_kernel(const Accum* __restrict__ acc, float* __restrict__ out) {
    float np = (float)acc->n_pos;
    float loc_loss = acc->loc_sl1 / (np * 4.0f);
    float conf_loss = (acc->conf_neg + acc->conf_pos) / np;
    out[0] = loc_loss + conf_loss;
}

extern "C" void kernel_launch(void* const* d_in, const int* in_sizes, int n_in,
                              void* d_out, int out_size, void* d_ws, size_t ws_size,
                              hipStream_t stream) {
    (void)in_sizes; (void)n_in; (void)out_size; (void)ws_size;
    const float4* loc_pred  = (const float4*)d_in[0];
    const float*  cls_pred  = (const float*)d_in[1];
    const float4* gt_boxes  = (const float4*)d_in[2];
    const int*    gt_labels = (const int*)d_in[3];
    const float4* db        = (const float4*)d_in[4];

    char* ws = (char*)d_ws;
    unsigned char* conf_t = (unsigned char*)ws;           // B*D bytes
    size_t off = ((size_t)BB * DD + 255) & ~(size_t)255;
    float* ce_neg = (float*)(ws + off);                   // B*D floats
    off += (size_t)BB * DD * sizeof(float);
    int* n_positive = (int*)(ws + off);                   // B ints
    off += (size_t)BB * sizeof(int);
    Accum* acc = (Accum*)(ws + off);

    hipMemsetAsync(acc, 0, sizeof(Accum), stream);

    match_kernel<<<BB, THREADS, 0, stream>>>(loc_pred, gt_boxes, gt_labels, db,
                                             conf_t, n_positive, acc);

    size_t total = (size_t)BB * DD;
    int blocks = (int)((total + THREADS - 1) / THREADS);
    ce_kernel<<<blocks, THREADS, 0, stream>>>(cls_pred, conf_t, ce_neg, acc);

    topk_kernel<<<BB, THREADS, 0, stream>>>(ce_neg, n_positive, acc);

    finalize_kernel<<<1, 1, 0, stream>>>(acc, (float*)d_out);
}